// Round 5
// baseline (128.115 us; speedup 1.0000x reference)
//
#include <hip/hip_runtime.h>
#include <stdint.h>
#include <math.h>

// Kuramoto dynamics, B=65536 x N=60, 10 steps.
// R8: instruction-granularity MFMA/VALU interleave of R7's dual-tile pipeline.
//   R4/R6/R7 invariant at 57-66us with VALU ~27% (real) + MFMA ~42% + ~30%
//   both-idle: in-order per-wave issue over COARSE blocks ([~96 MFMA][~350
//   VALU]) leaves each pipe idle during the other's block; 1.5-2 resident
//   phase-locked waves/SIMD don't fill the holes.
//   Fix: fuse at 4-MFMA granularity: per kt emit {4 MFMA; 1 update-elem of
//   the OTHER tile; 4 MFMA; 1 update-elem; ...}, next-kt pack ops in the
//   last two slots. A single in-order wave now feeds both pipes.
// Numerics bitwise-identical to R7/R6/R4/R3 (pure cross-chain reordering):
//   - per-acc MFMA product order per kt: AH.BH, AL.BH, AH.BL (kt 0..3)
//   - update: 4 separately-rounded f32 ops (#pragma clang fp contract(off))
//   - wrap: branch-free, boundary-exact (|x| >= f32(pi) predicate)
//   - theta-path exactness is a hard constraint: ~1e-6 perturbations cause
//     2pi wrap flips (~6 flips expected per 1e-6) -> output absmax 6.28.

#define B_TOTAL 65536
#define NOSC 60
#define STEPS 10

using short4v = __attribute__((ext_vector_type(4))) short;
using floatx4 = __attribute__((ext_vector_type(4))) float;

#if __has_builtin(__builtin_amdgcn_perm)
__device__ __forceinline__ unsigned int perm_b32(unsigned int s0, unsigned int s1, unsigned int sel) {
    return __builtin_amdgcn_perm(s0, s1, sel);
}
#else
__device__ __forceinline__ unsigned int perm_b32(unsigned int s0, unsigned int s1, unsigned int sel) {
    unsigned long long pool = ((unsigned long long)s0 << 32) | s1;
    unsigned int r = 0;
#pragma unroll
    for (int b = 0; b < 4; ++b) {
        unsigned int s = (sel >> (8 * b)) & 0xff;
        r |= ((unsigned int)((pool >> (8 * s)) & 0xff)) << (8 * b);
    }
    return r;
}
#endif

__device__ __forceinline__ unsigned int fbits(float x)        { return __builtin_bit_cast(unsigned int, x); }
__device__ __forceinline__ float        bitsf(unsigned int u) { return __builtin_bit_cast(float, u); }

#if __has_builtin(__builtin_amdgcn_mfma_f32_16x16x16bf16_1k)
__device__ __forceinline__ floatx4 mfma16(short4v a, short4v b, floatx4 c) {
    return __builtin_amdgcn_mfma_f32_16x16x16bf16_1k(a, b, c, 0, 0, 0);
}
#else
__device__ __forceinline__ floatx4 mfma16(short4v a, short4v b, floatx4 c) {
    asm("v_mfma_f32_16x16x16_bf16 %0, %1, %2, %0" : "+v"(c) : "v"(a), "v"(b));
    return c;
}
#endif

// pack bf16-hi(a) into low half, bf16-hi(b) into high half of one b32
__device__ __forceinline__ unsigned int pack_hi_pair(float a, float b) {
    return perm_b32(fbits(b), fbits(a), 0x07060302u);
}

// ---- pack one kt's SIN operands (hi pair + lo pair) into pk[0..3]
__device__ __forceinline__ void pack_kt_s(const float (&sn)[4][4], int kt, unsigned (&pk)[8]) {
    float slo[4];
#pragma unroll
    for (int r = 0; r < 4; ++r) {
        const unsigned us = fbits(sn[kt][r]);
        slo[r] = sn[kt][r] - bitsf(us & 0xffff0000u);
    }
    pk[0] = pack_hi_pair(sn[kt][0], sn[kt][1]);
    pk[1] = pack_hi_pair(sn[kt][2], sn[kt][3]);
    pk[2] = pack_hi_pair(slo[0], slo[1]);
    pk[3] = pack_hi_pair(slo[2], slo[3]);
}
// ---- pack one kt's COS operands into pk[4..7]
__device__ __forceinline__ void pack_kt_c(const float (&cn)[4][4], int kt, unsigned (&pk)[8]) {
    float clo[4];
#pragma unroll
    for (int r = 0; r < 4; ++r) {
        const unsigned uc = fbits(cn[kt][r]);
        clo[r] = cn[kt][r] - bitsf(uc & 0xffff0000u);
    }
    pk[4] = pack_hi_pair(cn[kt][0], cn[kt][1]);
    pk[5] = pack_hi_pair(cn[kt][2], cn[kt][3]);
    pk[6] = pack_hi_pair(clo[0], clo[1]);
    pk[7] = pack_hi_pair(clo[2], clo[3]);
}

// ---- one element's update: ref-exact association + boundary-exact wrap
__device__ __forceinline__ void update_elem(float (&th)[4][4], float (&sn)[4][4], float (&cn)[4][4],
                                            const float (&omg)[4][4],
                                            const floatx4 (&accS)[4], const floatx4 (&accC)[4],
                                            int nt, int r, float scale, float eff_dt)
{
    const float PI_F = 3.14159274101257324f;
    const float C_HI = 6.28318548202514648f;    // f32(2pi)
    const float C_LO = -1.7484556e-7f;          // 2pi - C_HI (f64-accurate)
    const float S = accS[nt][r];
    const float C = accC[nt][r];
    const float coup = cn[nt][r] * S - sn[nt][r] * C;  // approx path: fma ok
    float nth;
    {
#pragma clang fp contract(off)
        const float t1 = scale * coup;       // np: scale*coupling_sum
        const float t2 = omg[nt][r] + t1;    // np: omega + ...
        const float t3 = eff_dt * t2;        // np: eff_dt * (...)
        nth = th[nt][r] + t3;                // np: th + ...
    }
    float n = 0.0f;
    n = (nth >=  PI_F) ?  1.0f : n;
    n = (nth <= -PI_F) ? -1.0f : n;
    float y = fmaf(n, -C_HI, nth);
    y = fmaf(n, -C_LO, y);
    th[nt][r] = y;
    __sincosf(y, &sn[nt][r], &cn[nt][r]);
}

// ---- plain (non-interleaved) tile GEMM: used in the prologue only
__device__ __forceinline__ void mfma_tile(const short4v (&AH)[4][4], const short4v (&AL)[4][4],
                                          const float (&sn)[4][4], const float (&cn)[4][4],
                                          floatx4 (&accS)[4], floatx4 (&accC)[4])
{
    const floatx4 Z = (floatx4)0.0f;
#pragma unroll
    for (int kt = 0; kt < 4; ++kt) {
        unsigned pk[8];
        pack_kt_s(sn, kt, pk);
        pack_kt_c(cn, kt, pk);
        union PU { unsigned u[2]; short4v v; } vsh, vsl, vch, vcl;
        vsh.u[0] = pk[0]; vsh.u[1] = pk[1];
        vsl.u[0] = pk[2]; vsl.u[1] = pk[3];
        vch.u[0] = pk[4]; vch.u[1] = pk[5];
        vcl.u[0] = pk[6]; vcl.u[1] = pk[7];
#pragma unroll
        for (int nt = 0; nt < 4; ++nt) accS[nt] = mfma16(AH[nt][kt], vsh.v, (kt == 0) ? Z : accS[nt]);
#pragma unroll
        for (int nt = 0; nt < 4; ++nt) accC[nt] = mfma16(AH[nt][kt], vch.v, (kt == 0) ? Z : accC[nt]);
#pragma unroll
        for (int nt = 0; nt < 4; ++nt) accS[nt] = mfma16(AL[nt][kt], vsh.v, accS[nt]);
#pragma unroll
        for (int nt = 0; nt < 4; ++nt) accC[nt] = mfma16(AL[nt][kt], vcl.v == vcl.v ? vch.v : vch.v, accC[nt]);
#pragma unroll
        for (int nt = 0; nt < 4; ++nt) accS[nt] = mfma16(AH[nt][kt], vsl.v, accS[nt]);
#pragma unroll
        for (int nt = 0; nt < 4; ++nt) accC[nt] = mfma16(AH[nt][kt], vcl.v, accC[nt]);
    }
}

// ---- plain tile update: used in the tail only
__device__ __forceinline__ void update_tile(float (&th)[4][4], float (&sn)[4][4], float (&cn)[4][4],
                                            const float (&omg)[4][4],
                                            const floatx4 (&accS)[4], const floatx4 (&accC)[4],
                                            float scale, float eff_dt)
{
#pragma unroll
    for (int nt = 0; nt < 4; ++nt)
#pragma unroll
        for (int r = 0; r < 4; ++r)
            update_elem(th, sn, cn, omg, accS, accC, nt, r, scale, eff_dt);
}

// ---- interleaved half-step: MFMA of tile M fused (4-MFMA granularity) with
// update of tile U. pk0 holds M's kt=0 packed operands (from previous half);
// pkNext receives U's (post-update) kt=0 pack for the NEXT half.
__device__ __forceinline__ void half_step(
    const short4v (&AH)[4][4], const short4v (&AL)[4][4],
    const float (&snM)[4][4], const float (&cnM)[4][4],
    floatx4 (&accSM)[4], floatx4 (&accCM)[4],
    float (&thU)[4][4], float (&snU)[4][4], float (&cnU)[4][4],
    const floatx4 (&accSU)[4], const floatx4 (&accCU)[4],
    const float (&omg)[4][4], float scale, float eff_dt,
    const unsigned (&pk0)[8], unsigned (&pkNext)[8])
{
    const floatx4 Z = (floatx4)0.0f;
    unsigned cur[8], nxt[8];
#pragma unroll
    for (int i = 0; i < 8; ++i) cur[i] = pk0[i];
#pragma unroll
    for (int kt = 0; kt < 4; ++kt) {
        union PU { unsigned u[2]; short4v v; } vsh, vsl, vch, vcl;
        vsh.u[0] = cur[0]; vsh.u[1] = cur[1];
        vsl.u[0] = cur[2]; vsl.u[1] = cur[3];
        vch.u[0] = cur[4]; vch.u[1] = cur[5];
        vcl.u[0] = cur[6]; vcl.u[1] = cur[7];
        // 6 MFMA groups of tile M, interleaved with 4 update elems of tile U
        // (nt=kt) and the next kt's pack. Per-acc product order unchanged.
#pragma unroll
        for (int nt = 0; nt < 4; ++nt) accSM[nt] = mfma16(AH[nt][kt], vsh.v, (kt == 0) ? Z : accSM[nt]);
        update_elem(thU, snU, cnU, omg, accSU, accCU, kt, 0, scale, eff_dt);
#pragma unroll
        for (int nt = 0; nt < 4; ++nt) accCM[nt] = mfma16(AH[nt][kt], vch.v, (kt == 0) ? Z : accCM[nt]);
        update_elem(thU, snU, cnU, omg, accSU, accCU, kt, 1, scale, eff_dt);
#pragma unroll
        for (int nt = 0; nt < 4; ++nt) accSM[nt] = mfma16(AL[nt][kt], vsh.v, accSM[nt]);
        update_elem(thU, snU, cnU, omg, accSU, accCU, kt, 2, scale, eff_dt);
#pragma unroll
        for (int nt = 0; nt < 4; ++nt) accCM[nt] = mfma16(AL[nt][kt], vch.v, accCM[nt]);
        update_elem(thU, snU, cnU, omg, accSU, accCU, kt, 3, scale, eff_dt);
#pragma unroll
        for (int nt = 0; nt < 4; ++nt) accSM[nt] = mfma16(AH[nt][kt], vsl.v, accSM[nt]);
        if (kt < 3) pack_kt_s(snM, kt + 1, nxt);
        else        pack_kt_s(snU, 0, pkNext);     // U's nt=0 was updated at kt=0
#pragma unroll
        for (int nt = 0; nt < 4; ++nt) accCM[nt] = mfma16(AH[nt][kt], vcl.v, accCM[nt]);
        if (kt < 3) {
            pack_kt_c(cnM, kt + 1, nxt);
#pragma unroll
            for (int i = 0; i < 8; ++i) cur[i] = nxt[i];
        } else {
            pack_kt_c(cnU, 0, pkNext);
        }
    }
}

__global__ __launch_bounds__(64)
void kuramoto_kernel(const float* __restrict__ theta_in,
                     const float* __restrict__ Kmat,
                     const float* __restrict__ omega,
                     const float* __restrict__ p_kglobal,
                     const float* __restrict__ p_cmod,
                     const float* __restrict__ p_gate,
                     const float* __restrict__ p_slow,
                     const float* __restrict__ p_dsneg,
                     const float* __restrict__ p_relax,
                     float* __restrict__ theta_out,
                     float* __restrict__ coh_out)
{
    const int lane = threadIdx.x & 63;
    const int lidx = lane & 15;          // batch within tile
    const int quad = lane >> 4;          // 0..3

    const float kglobal = p_kglobal[0];
    const float cmod    = p_cmod[0];
    const float gate    = p_gate[0];
    const float slow    = p_slow[0];
    const float dsneg   = p_dsneg[0];
    const float relax   = p_relax[0];

    float eff_dt, scale;
    {
#pragma clang fp contract(off)
        const float a     = slow * relax;
        const float b     = 1.0f + a;
        const float crit  = 1.0f / b;
        eff_dt            = 0.1f * crit;
        const float boost = 1.0f + gate * dsneg;
        scale             = (kglobal * boost) / 60.0f;
    }

    const int batch0A = blockIdx.x * 32;
    const int batch0B = batch0A + 16;
    const int browA   = (batch0A + lidx) * NOSC;
    const int browB   = (batch0B + lidx) * NOSC;

    // ---- A operand (loop-invariant, shared by both tiles): Ke = K*cmod,
    // MFMA-A layout, hi/lo split. lane row i = nt*16+lidx, k = kt*16+quad*4+j.
    short4v AH[4][4], AL[4][4];
#pragma unroll
    for (int nt = 0; nt < 4; ++nt) {
        const int i = nt * 16 + lidx;
        const bool okn = (i < NOSC);          // zero A rows >= 60 -> acc rows 60..63 = 0
#pragma unroll
        for (int kt = 0; kt < 4; ++kt) {
            const int k0 = kt * 16 + quad * 4;
            float kv[4];
            if (okn && (k0 + 3) < NOSC) {
                const float4 a = *(const float4*)(Kmat + i * NOSC + k0);
                kv[0] = a.x; kv[1] = a.y; kv[2] = a.z; kv[3] = a.w;
            } else {
#pragma unroll
                for (int j = 0; j < 4; ++j)
                    kv[j] = (okn && (k0 + j) < NOSC) ? Kmat[i * NOSC + k0 + j] : 0.0f;
            }
            short4v h, l;
#pragma unroll
            for (int j = 0; j < 4; ++j) {
                const float v = kv[j] * cmod;
                const unsigned int hb = fbits(v) & 0xffff0000u;
                const float rlo = v - bitsf(hb);
                h[j] = (short)(hb >> 16);
                l[j] = (short)(fbits(rlo) >> 16);
            }
            AH[nt][kt] = h;
            AL[nt][kt] = l;
        }
    }

    // ---- state, C/D layout: element (osc o = nt*16 + quad*4 + r, batch lidx)
    float thA[4][4], snA[4][4], cnA[4][4];
    float thB[4][4], snB[4][4], cnB[4][4];
    float omg[4][4];                       // osc-indexed: shared by both tiles
#pragma unroll
    for (int nt = 0; nt < 4; ++nt) {
        const int o0 = nt * 16 + quad * 4;    // {0,4,..,56} or 60 (pad)
        if (o0 + 3 < NOSC) {
            const float4 ov = *(const float4*)(omega + o0);
            omg[nt][0] = ov.x; omg[nt][1] = ov.y; omg[nt][2] = ov.z; omg[nt][3] = ov.w;
            const float4 ta = *(const float4*)(theta_in + browA + o0);
            thA[nt][0] = ta.x; thA[nt][1] = ta.y; thA[nt][2] = ta.z; thA[nt][3] = ta.w;
            const float4 tb = *(const float4*)(theta_in + browB + o0);
            thB[nt][0] = tb.x; thB[nt][1] = tb.y; thB[nt][2] = tb.z; thB[nt][3] = tb.w;
        } else {
#pragma unroll
            for (int r = 0; r < 4; ++r) {
                omg[nt][r] = 0.0f; thA[nt][r] = 0.0f; thB[nt][r] = 0.0f;
            }
        }
#pragma unroll
        for (int r = 0; r < 4; ++r) {
            __sincosf(thA[nt][r], &snA[nt][r], &cnA[nt][r]);
            __sincosf(thB[nt][r], &snB[nt][r], &cnB[nt][r]);
        }
    }

    floatx4 accSA[4], accCA[4], accSB[4], accCB[4];
    unsigned pkA0[8], pkB0[8];

    // ---- prologue: A's step-0 GEMM (plain), then pack B's kt=0 operands
    mfma_tile(AH, AL, snA, cnA, accSA, accCA);
    pack_kt_s(snB, 0, pkB0);
    pack_kt_c(cnB, 0, pkB0);

    // ---- steady state: two interleaved halves per step
#pragma unroll 1
    for (int t = 0; t < STEPS - 1; ++t) {
        // mfma B(t) fused with update A(t);  packs A(0) for next half
        half_step(AH, AL, snB, cnB, accSB, accCB,
                  thA, snA, cnA, accSA, accCA, omg, scale, eff_dt, pkB0, pkA0);
        // mfma A(t+1) fused with update B(t); packs B(0) for next iteration
        half_step(AH, AL, snA, cnA, accSA, accCA,
                  thB, snB, cnB, accSB, accCB, omg, scale, eff_dt, pkA0, pkB0);
    }
    // ---- tail: mfma B(9) fused with update A(9), then plain update B(9)
    half_step(AH, AL, snB, cnB, accSB, accCB,
              thA, snA, cnA, accSA, accCA, omg, scale, eff_dt, pkB0, pkA0);
    update_tile(thB, snB, cnB, omg, accSB, accCB, scale, eff_dt);

    // ---- epilogue: store wrapped theta (float4 per nt, pad tile skipped)
#pragma unroll
    for (int nt = 0; nt < 4; ++nt) {
        const int o0 = nt * 16 + quad * 4;
        if (o0 + 3 < NOSC) {
            float4 ta, tb;
            ta.x = thA[nt][0]; ta.y = thA[nt][1]; ta.z = thA[nt][2]; ta.w = thA[nt][3];
            *(float4*)(theta_out + browA + o0) = ta;
            tb.x = thB[nt][0]; tb.y = thB[nt][1]; tb.z = thB[nt][2]; tb.w = thB[nt][3];
            *(float4*)(theta_out + browB + o0) = tb;
        }
    }

    // ---- coherence per tile: batch = lidx; 16 osc local, 48 in sibling quads.
    float pcA = 0.0f, psA = 0.0f, pcB = 0.0f, psB = 0.0f;
#pragma unroll
    for (int nt = 0; nt < 4; ++nt) {
        if (nt * 16 + quad * 4 < NOSC) {   // skip pad osc 60..63 (cos(0)=1!)
#pragma unroll
            for (int r = 0; r < 4; ++r) {
                pcA += cnA[nt][r]; psA += snA[nt][r];
                pcB += cnB[nt][r]; psB += snB[nt][r];
            }
        }
    }
    pcA += __shfl_xor(pcA, 16); psA += __shfl_xor(psA, 16);
    pcA += __shfl_xor(pcA, 32); psA += __shfl_xor(psA, 32);
    pcB += __shfl_xor(pcB, 16); psB += __shfl_xor(psB, 16);
    pcB += __shfl_xor(pcB, 32); psB += __shfl_xor(psB, 32);
    if (quad == 0) {
        const float cmA = pcA / 60.0f, smA = psA / 60.0f;
        coh_out[batch0A + lidx] = sqrtf(cmA * cmA + smA * smA);
        const float cmB = pcB / 60.0f, smB = psB / 60.0f;
        coh_out[batch0B + lidx] = sqrtf(cmB * cmB + smB * smB);
    }
}

extern "C" void kernel_launch(void* const* d_in, const int* in_sizes, int n_in,
                              void* d_out, int out_size, void* d_ws, size_t ws_size,
                              hipStream_t stream) {
    const float* theta = (const float*)d_in[0];
    const float* Kmat  = (const float*)d_in[1];
    const float* omg   = (const float*)d_in[2];
    const float* kg    = (const float*)d_in[3];
    const float* cmod  = (const float*)d_in[4];
    const float* gate  = (const float*)d_in[5];
    const float* slow  = (const float*)d_in[6];
    const float* dsn   = (const float*)d_in[7];
    const float* relax = (const float*)d_in[8];
    float* out = (float*)d_out;

    kuramoto_kernel<<<dim3(B_TOTAL / 32), dim3(64), 0, stream>>>(
        theta, Kmat, omg, kg, cmod, gate, slow, dsn, relax,
        out, out + (size_t)B_TOTAL * NOSC);
}

// Round 7
// 119.975 us; speedup vs baseline: 1.0678x; 1.0678x over previous
//
#include <hip/hip_runtime.h>
#include <stdint.h>
#include <math.h>

// Kuramoto dynamics, B=65536 x N=60, 10 steps.
// R10: 32x32x16 MFMA, exchange-free (fixes R9's correctness failure).
//   R9 failed with absmax 6.28 (2pi wrap flips): the permlane32_swap-based
//   B-half exchange depended on a GUESSED builtin return convention; if
//   flipped, products pair Ke[o]*sin[o+-4] -> scrambled coupling -> flips.
//   Fix: eliminate the exchange entirely. MFMA pairs A-slot(h,j) with
//   B-slot(h,j); the hardware k numbering cancels when A and B agree
//   slot-wise. The C/D layout already gives B-slot(h,j) = state elem j
//   (osc = 16kb + (j&3) + 8(j>>2) + 4h) with IDENTITY packing; we gather
//   A-slot(h,j) = Ke[m][16kb + (j&3) + 8(j>>2) + 4h] at load time (free,
//   loop-invariant). Zero cross-lane ops in the loop; no semantics risk.
//   Also removes R9's 32 exchange + 96 select ops/step.
//   MFMA bill halves vs R8: 192 x 3.84cyc -> 48 x 8.07cyc per 32-batch step
//   (wall ~= sum of MFMA+VALU issue cycles per R4-R8 post-mortems).
// Numerics per element identical to R3-R8:
//   - 3-product split: KH.sH + KL.sH + KH.sL, 16-k chunks in order kb=0..3
//   - update: 4 separately-rounded f32 ops (#pragma clang fp contract(off))
//   - wrap: branch-free, boundary-exact (|x| >= f32(pi) predicate)
//   - HW __sincosf only on paths attenuated by eff_dt*scale ~1e-3

#define B_TOTAL 65536
#define NOSC 60
#define STEPS 10

using short8v  = __attribute__((ext_vector_type(8))) short;
using floatx16 = __attribute__((ext_vector_type(16))) float;
using bf16x8   = __attribute__((ext_vector_type(8))) __bf16;

#if __has_builtin(__builtin_amdgcn_perm)
__device__ __forceinline__ unsigned int perm_b32(unsigned int s0, unsigned int s1, unsigned int sel) {
    return __builtin_amdgcn_perm(s0, s1, sel);
}
#else
__device__ __forceinline__ unsigned int perm_b32(unsigned int s0, unsigned int s1, unsigned int sel) {
    unsigned long long pool = ((unsigned long long)s0 << 32) | s1;
    unsigned int r = 0;
#pragma unroll
    for (int b = 0; b < 4; ++b) {
        unsigned int s = (sel >> (8 * b)) & 0xff;
        r |= ((unsigned int)((pool >> (8 * s)) & 0xff)) << (8 * b);
    }
    return r;
}
#endif

__device__ __forceinline__ unsigned int fbits(float x)        { return __builtin_bit_cast(unsigned int, x); }
__device__ __forceinline__ float        bitsf(unsigned int u) { return __builtin_bit_cast(float, u); }

// 32x32x16 bf16 MFMA. Builtin if present (v8bf16 operands), else inline asm.
__device__ __forceinline__ floatx16 mfma32(short8v a, short8v b, floatx16 c) {
#if __has_builtin(__builtin_amdgcn_mfma_f32_32x32x16_bf16)
    return __builtin_amdgcn_mfma_f32_32x32x16_bf16(
        __builtin_bit_cast(bf16x8, a), __builtin_bit_cast(bf16x8, b), c, 0, 0, 0);
#else
    asm("v_mfma_f32_32x32x16_bf16 %0, %1, %2, %0" : "+v"(c) : "v"(a), "v"(b));
    return c;
#endif
}

// pack bf16-hi(a) into low half, bf16-hi(b) into high half of one b32
__device__ __forceinline__ unsigned int pack_hi_pair(float a, float b) {
    return perm_b32(fbits(b), fbits(a), 0x07060302u);
}

__global__ __launch_bounds__(64)
void kuramoto_kernel(const float* __restrict__ theta_in,
                     const float* __restrict__ Kmat,
                     const float* __restrict__ omega,
                     const float* __restrict__ p_kglobal,
                     const float* __restrict__ p_cmod,
                     const float* __restrict__ p_gate,
                     const float* __restrict__ p_slow,
                     const float* __restrict__ p_dsneg,
                     const float* __restrict__ p_relax,
                     float* __restrict__ theta_out,
                     float* __restrict__ coh_out)
{
    const int lane = threadIdx.x & 63;
    const int c    = lane & 31;   // batch within tile (A row-lane, B col-lane, C/D col)
    const int h    = lane >> 5;   // lane half

    const float kglobal = p_kglobal[0];
    const float cmod    = p_cmod[0];
    const float gate    = p_gate[0];
    const float slow    = p_slow[0];
    const float dsneg   = p_dsneg[0];
    const float relax   = p_relax[0];

    float eff_dt, scale;
    {
#pragma clang fp contract(off)
        const float a     = slow * relax;
        const float b     = 1.0f + a;
        const float crit  = 1.0f / b;
        eff_dt            = 0.1f * crit;
        const float boost = 1.0f + gate * dsneg;
        scale             = (kglobal * boost) / 60.0f;
    }

    const int batch0 = blockIdx.x * 32;
    const int brow   = (batch0 + c) * NOSC;

    // ---- A operand (loop-invariant): Ke = K*cmod, hi/lo trunc split, with
    // sigma-gathered k columns chosen to match the NATURAL B packing:
    //   A slot (h, j) = Ke[m][ 16*kb + (j&3) + 8*(j>>2) + 4*h ]
    // so that B slot (h, j) = state elem j (identity packing, no exchange).
    // Slot-consistency makes the result independent of the HW's internal
    // k numbering (same argument that made R3-R8's layouts robust).
    short8v AH[2][4], AL[2][4];
#pragma unroll
    for (int ob = 0; ob < 2; ++ob) {
        const int m = 32 * ob + c;
        const bool okm = (m < NOSC);          // zero rows >= 60 -> acc rows 60..63 = 0
#pragma unroll
        for (int kb = 0; kb < 4; ++kb) {
            const int base = 16 * kb + 4 * h;   // j=0..3 -> base+j; j=4..7 -> base+8+(j-4)
            float kv[8];
            if (okm && (base + 11) < NOSC) {
                const float4 a = *(const float4*)(Kmat + m * NOSC + base);
                const float4 b = *(const float4*)(Kmat + m * NOSC + base + 8);
                kv[0]=a.x; kv[1]=a.y; kv[2]=a.z; kv[3]=a.w;
                kv[4]=b.x; kv[5]=b.y; kv[6]=b.z; kv[7]=b.w;
            } else {
#pragma unroll
                for (int j = 0; j < 8; ++j) {
                    const int col = base + (j & 3) + 8 * (j >> 2);
                    kv[j] = (okm && col < NOSC) ? Kmat[m * NOSC + col] : 0.0f;
                }
            }
            short8v hh, ll;
#pragma unroll
            for (int j = 0; j < 8; ++j) {
                const float v = kv[j] * cmod;
                const unsigned int hb = fbits(v) & 0xffff0000u;
                const float rlo = v - bitsf(hb);
                hh[j] = (short)(hb >> 16);
                ll[j] = (short)(fbits(rlo) >> 16);
            }
            AH[ob][kb] = hh;
            AL[ob][kb] = ll;
        }
    }

    // ---- state in 32x32 C/D layout: elem (ob, reg) holds
    //   osc o = 32*ob + (reg&3) + 8*(reg>>2) + 4*h, batch = batch0 + c
    float th[2][16], sn[2][16], cn[2][16], omg[2][16];
#pragma unroll
    for (int ob = 0; ob < 2; ++ob) {
#pragma unroll
        for (int g = 0; g < 4; ++g) {
            const int o0 = 32 * ob + 8 * g + 4 * h;
            const int rb = 4 * g;
            if (o0 + 3 < NOSC) {               // pad only (ob=1,g=3,h=1): osc 60-63
                const float4 tv = *(const float4*)(theta_in + brow + o0);
                const float4 ov = *(const float4*)(omega + o0);
                th[ob][rb+0] = tv.x; th[ob][rb+1] = tv.y; th[ob][rb+2] = tv.z; th[ob][rb+3] = tv.w;
                omg[ob][rb+0] = ov.x; omg[ob][rb+1] = ov.y; omg[ob][rb+2] = ov.z; omg[ob][rb+3] = ov.w;
            } else {
#pragma unroll
                for (int m = 0; m < 4; ++m) { th[ob][rb+m] = 0.0f; omg[ob][rb+m] = 0.0f; }
            }
#pragma unroll
            for (int m = 0; m < 4; ++m)
                __sincosf(th[ob][rb+m], &sn[ob][rb+m], &cn[ob][rb+m]);
        }
    }

    // wrap constants (boundary-exact, see R3 notes)
    const float PI_F = 3.14159274101257324f;
    const float C_HI = 6.28318548202514648f;    // f32(2pi)
    const float C_LO = -1.7484556e-7f;          // 2pi - C_HI (f64-accurate)

#pragma unroll 1
    for (int t = 0; t < STEPS; ++t) {
        floatx16 aS0, aS1, aC0, aC1;
        const floatx16 Z = (floatx16)0.0f;

#pragma unroll
        for (int kb = 0; kb < 4; ++kb) {
            // B source: state elems (obp, r0+j), j=0..7 -- IDENTITY packing.
            // B slot (h,j) holds osc 16kb + (j&3) + 8(j>>2) + 4h, matching
            // the sigma-gathered A columns slot-for-slot.
            const int obp = kb >> 1;
            const int r0  = (kb & 1) * 8;

            float sl_[8], cl_[8];
#pragma unroll
            for (int s = 0; s < 8; ++s) {
                const unsigned us = fbits(sn[obp][r0+s]);
                sl_[s] = sn[obp][r0+s] - bitsf(us & 0xffff0000u);
                const unsigned uc = fbits(cn[obp][r0+s]);
                cl_[s] = cn[obp][r0+s] - bitsf(uc & 0xffff0000u);
            }
            union BU { unsigned u[4]; short8v v; };
            BU Bsh, Bsl, Bch, Bcl;
#pragma unroll
            for (int p = 0; p < 4; ++p) {
                Bsh.u[p] = pack_hi_pair(sn[obp][r0+2*p], sn[obp][r0+2*p+1]);
                Bsl.u[p] = pack_hi_pair(sl_[2*p], sl_[2*p+1]);
                Bch.u[p] = pack_hi_pair(cn[obp][r0+2*p], cn[obp][r0+2*p+1]);
                Bcl.u[p] = pack_hi_pair(cl_[2*p], cl_[2*p+1]);
            }

            // 12 MFMAs, product-major S/C interleave (same-acc distance 4).
            // Per-acc product order: H.BH, L.BH, H.BL -- unchanged.
            aS0 = mfma32(AH[0][kb], Bsh.v, (kb == 0) ? Z : aS0);
            aS1 = mfma32(AH[1][kb], Bsh.v, (kb == 0) ? Z : aS1);
            aC0 = mfma32(AH[0][kb], Bch.v, (kb == 0) ? Z : aC0);
            aC1 = mfma32(AH[1][kb], Bch.v, (kb == 0) ? Z : aC1);
            aS0 = mfma32(AL[0][kb], Bsh.v, aS0);
            aS1 = mfma32(AL[1][kb], Bsh.v, aS1);
            aC0 = mfma32(AL[0][kb], Bch.v, aC0);
            aC1 = mfma32(AL[1][kb], Bch.v, aC1);
            aS0 = mfma32(AH[0][kb], Bsl.v, aS0);
            aS1 = mfma32(AH[1][kb], Bsl.v, aS1);
            aC0 = mfma32(AH[0][kb], Bcl.v, aC0);
            aC1 = mfma32(AH[1][kb], Bcl.v, aC1);
        }

        // ---- update: ref-exact association + boundary-exact wrap
#pragma unroll
        for (int ob = 0; ob < 2; ++ob) {
            const floatx16 &aS = ob ? aS1 : aS0;
            const floatx16 &aC = ob ? aC1 : aC0;
#pragma unroll
            for (int r = 0; r < 16; ++r) {
                const float S = aS[r];
                const float C = aC[r];
                const float coup = cn[ob][r] * S - sn[ob][r] * C;  // approx path: fma ok
                float nth;
                {
#pragma clang fp contract(off)
                    const float t1 = scale * coup;       // np: scale*coupling_sum
                    const float t2 = omg[ob][r] + t1;    // np: omega + ...
                    const float t3 = eff_dt * t2;        // np: eff_dt * (...)
                    nth = th[ob][r] + t3;                // np: th + ...
                }
                float n = 0.0f;
                n = (nth >=  PI_F) ?  1.0f : n;
                n = (nth <= -PI_F) ? -1.0f : n;
                float y = fmaf(n, -C_HI, nth);
                y = fmaf(n, -C_LO, y);
                th[ob][r] = y;
                __sincosf(y, &sn[ob][r], &cn[ob][r]);
            }
        }
    }

    // ---- epilogue: store wrapped theta (float4 per (ob,g), pad chunk skipped)
#pragma unroll
    for (int ob = 0; ob < 2; ++ob) {
#pragma unroll
        for (int g = 0; g < 4; ++g) {
            const int o0 = 32 * ob + 8 * g + 4 * h;
            const int rb = 4 * g;
            if (o0 + 3 < NOSC) {
                float4 tv;
                tv.x = th[ob][rb+0]; tv.y = th[ob][rb+1];
                tv.z = th[ob][rb+2]; tv.w = th[ob][rb+3];
                *(float4*)(theta_out + brow + o0) = tv;
            }
        }
    }

    // ---- coherence: batch = batch0 + c split across lane halves.
    // Pad elems (ob=1, regs 12-15, h=1) hold exactly (sn,cn)=(0,1) forever
    // (A rows >= 60 zeroed -> coup=0, omg=0, th stays 0): sum all 32 then
    // subtract the 4 pad cosines at h==1.
    float pc = 0.0f, ps = 0.0f;
#pragma unroll
    for (int ob = 0; ob < 2; ++ob)
#pragma unroll
        for (int r = 0; r < 16; ++r) { pc += cn[ob][r]; ps += sn[ob][r]; }
    pc -= h ? 4.0f : 0.0f;
    pc += __shfl_xor(pc, 32);
    ps += __shfl_xor(ps, 32);
    if (h == 0) {
        const float cm = pc / 60.0f;
        const float sm = ps / 60.0f;
        coh_out[batch0 + c] = sqrtf(cm * cm + sm * sm);
    }
}

extern "C" void kernel_launch(void* const* d_in, const int* in_sizes, int n_in,
                              void* d_out, int out_size, void* d_ws, size_t ws_size,
                              hipStream_t stream) {
    const float* theta = (const float*)d_in[0];
    const float* Kmat  = (const float*)d_in[1];
    const float* omg   = (const float*)d_in[2];
    const float* kg    = (const float*)d_in[3];
    const float* cmod  = (const float*)d_in[4];
    const float* gate  = (const float*)d_in[5];
    const float* slow  = (const float*)d_in[6];
    const float* dsn   = (const float*)d_in[7];
    const float* relax = (const float*)d_in[8];
    float* out = (float*)d_out;

    kuramoto_kernel<<<dim3(B_TOTAL / 32), dim3(64), 0, stream>>>(
        theta, Kmat, omg, kg, cmod, gate, slow, dsn, relax,
        out, out + (size_t)B_TOTAL * NOSC);
}